// Round 4
// baseline (462.748 us; speedup 1.0000x reference)
//
#include <hip/hip_runtime.h>

// Inverse 2D Haar wavelet:
//   in : (B=16, 4*CH=256, H=128, W=128) f32
//   out: (B=16, CH=64,   2H=256, 2W=256) f32
// out[b,c,2h+0,2w+0] = (LL+LH+HL+HH)*0.5
// out[b,c,2h+0,2w+1] = (LL+LH-HL-HH)*0.5
// out[b,c,2h+1,2w+0] = (LL-LH+HL-HH)*0.5
// out[b,c,2h+1,2w+1] = (LL-LH-HL+HH)*0.5
//
// R3: same as R2 but nontemporal builtins need a native clang vector type,
// not HIP_vector_type<float,4> — use ext_vector_type(4).

typedef float vf4 __attribute__((ext_vector_type(4)));

__global__ __launch_bounds__(256) void iwt2d_kernel(const float* __restrict__ x,
                                                    float* __restrict__ out) {
    constexpr int B = 16, CH = 64, H = 128, W = 128;
    constexpr int WG = W / 8;                       // 16 groups of 8 floats per row
    const int t = blockIdx.x * blockDim.x + threadIdx.x;
    // total threads = B*CH*H*WG = 16*64*128*16 = 2,097,152 (grid sized exactly)
    const int wq = t & (WG - 1);
    const int h  = (t >> 4) & (H - 1);
    const int c  = (t >> 11) & (CH - 1);
    const int b  = t >> 17;
    if (b >= B) return;

    const size_t plane = (size_t)H * W;             // 16384
    const float* base = x + (size_t)b * (4 * CH) * plane + (size_t)c * plane
                          + (size_t)h * W + (size_t)wq * 8;
    const float* pll = base;
    const float* plh = base + (size_t)CH * plane;
    const float* phl = base + (size_t)(2 * CH) * plane;
    const float* phh = base + (size_t)(3 * CH) * plane;

    float ll[8], lh[8], hl[8], hh[8];
    *(vf4*)&ll[0] = __builtin_nontemporal_load((const vf4*)(pll));
    *(vf4*)&ll[4] = __builtin_nontemporal_load((const vf4*)(pll + 4));
    *(vf4*)&lh[0] = __builtin_nontemporal_load((const vf4*)(plh));
    *(vf4*)&lh[4] = __builtin_nontemporal_load((const vf4*)(plh + 4));
    *(vf4*)&hl[0] = __builtin_nontemporal_load((const vf4*)(phl));
    *(vf4*)&hl[4] = __builtin_nontemporal_load((const vf4*)(phl + 4));
    *(vf4*)&hh[0] = __builtin_nontemporal_load((const vf4*)(phh));
    *(vf4*)&hh[4] = __builtin_nontemporal_load((const vf4*)(phh + 4));

    // top row (a,b interleaved) and bottom row (c,d interleaved), 16 floats each
    float top[16], bot[16];
#pragma unroll
    for (int j = 0; j < 8; ++j) {
        const float s0 = ll[j] + lh[j];   // LL+LH
        const float s1 = ll[j] - lh[j];   // LL-LH
        const float s2 = hl[j] + hh[j];   // HL+HH
        const float s3 = hl[j] - hh[j];   // HL-HH
        top[2 * j + 0] = (s0 + s2) * 0.5f;   // a
        top[2 * j + 1] = (s0 - s2) * 0.5f;   // b
        bot[2 * j + 0] = (s1 + s3) * 0.5f;   // c
        bot[2 * j + 1] = (s1 - s3) * 0.5f;   // d
    }

    const size_t oW = 2 * W;                        // 256
    const size_t oplane = (size_t)(2 * H) * oW;     // 131072
    float* orow0 = out + (size_t)b * CH * oplane + (size_t)c * oplane
                       + (size_t)(2 * h) * oW + (size_t)wq * 16;
    float* orow1 = orow0 + oW;

#pragma unroll
    for (int q = 0; q < 4; ++q) {
        __builtin_nontemporal_store(*(const vf4*)&top[4 * q], (vf4*)(orow0 + 4 * q));
        __builtin_nontemporal_store(*(const vf4*)&bot[4 * q], (vf4*)(orow1 + 4 * q));
    }
}

extern "C" void kernel_launch(void* const* d_in, const int* in_sizes, int n_in,
                              void* d_out, int out_size, void* d_ws, size_t ws_size,
                              hipStream_t stream) {
    const float* x = (const float*)d_in[0];
    float* out = (float*)d_out;
    constexpr int total_threads = 16 * 64 * 128 * 16;   // 2,097,152
    constexpr int block = 256;
    constexpr int grid = total_threads / block;          // 8192
    iwt2d_kernel<<<grid, block, 0, stream>>>(x, out);
}

// Round 5
// 131.846 us; speedup vs baseline: 3.5098x; 3.5098x over previous
//
#include <hip/hip_runtime.h>

// Inverse 2D Haar wavelet:
//   in : (B=16, 4*CH=256, H=128, W=128) f32
//   out: (B=16, CH=64,   2H=256, 2W=256) f32
// out[b,c,2h+0,2w+0] = (LL+LH+HL+HH)*0.5
// out[b,c,2h+0,2w+1] = (LL+LH-HL-HH)*0.5
// out[b,c,2h+1,2w+0] = (LL-LH+HL-HH)*0.5
// out[b,c,2h+1,2w+1] = (LL-LH-HL+HH)*0.5
//
// R4 lesson: nontemporal (nt) stores on gfx950 bypass L2 write-combining ->
// WRITE_SIZE 2.4x inflation, 4.4x slower. Plain write-back stores ARE the
// write combiner. This round: plain float4 everywhere, keep 8-wide ILP.

__global__ __launch_bounds__(256) void iwt2d_kernel(const float* __restrict__ x,
                                                    float* __restrict__ out) {
    constexpr int B = 16, CH = 64, H = 128, W = 128;
    constexpr int WG = W / 8;                       // 16 groups of 8 floats per row
    const int t = blockIdx.x * blockDim.x + threadIdx.x;
    // total threads = B*CH*H*WG = 16*64*128*16 = 2,097,152 (grid sized exactly)
    const int wq = t & (WG - 1);
    const int h  = (t >> 4) & (H - 1);
    const int c  = (t >> 11) & (CH - 1);
    const int b  = t >> 17;
    if (b >= B) return;

    const size_t plane = (size_t)H * W;             // 16384
    const float* base = x + (size_t)b * (4 * CH) * plane + (size_t)c * plane
                          + (size_t)h * W + (size_t)wq * 8;
    const float* pll = base;
    const float* plh = base + (size_t)CH * plane;
    const float* phl = base + (size_t)(2 * CH) * plane;
    const float* phh = base + (size_t)(3 * CH) * plane;

    float ll[8], lh[8], hl[8], hh[8];
    *(float4*)&ll[0] = *(const float4*)(pll);
    *(float4*)&ll[4] = *(const float4*)(pll + 4);
    *(float4*)&lh[0] = *(const float4*)(plh);
    *(float4*)&lh[4] = *(const float4*)(plh + 4);
    *(float4*)&hl[0] = *(const float4*)(phl);
    *(float4*)&hl[4] = *(const float4*)(phl + 4);
    *(float4*)&hh[0] = *(const float4*)(phh);
    *(float4*)&hh[4] = *(const float4*)(phh + 4);

    // top row (a,b interleaved) and bottom row (c,d interleaved), 16 floats each
    float top[16], bot[16];
#pragma unroll
    for (int j = 0; j < 8; ++j) {
        const float s0 = ll[j] + lh[j];   // LL+LH
        const float s1 = ll[j] - lh[j];   // LL-LH
        const float s2 = hl[j] + hh[j];   // HL+HH
        const float s3 = hl[j] - hh[j];   // HL-HH
        top[2 * j + 0] = (s0 + s2) * 0.5f;   // a
        top[2 * j + 1] = (s0 - s2) * 0.5f;   // b
        bot[2 * j + 0] = (s1 + s3) * 0.5f;   // c
        bot[2 * j + 1] = (s1 - s3) * 0.5f;   // d
    }

    const size_t oW = 2 * W;                        // 256
    const size_t oplane = (size_t)(2 * H) * oW;     // 131072
    float* orow0 = out + (size_t)b * CH * oplane + (size_t)c * oplane
                       + (size_t)(2 * h) * oW + (size_t)wq * 16;
    float* orow1 = orow0 + oW;

#pragma unroll
    for (int q = 0; q < 4; ++q) {
        *(float4*)(orow0 + 4 * q) = *(const float4*)&top[4 * q];
        *(float4*)(orow1 + 4 * q) = *(const float4*)&bot[4 * q];
    }
}

extern "C" void kernel_launch(void* const* d_in, const int* in_sizes, int n_in,
                              void* d_out, int out_size, void* d_ws, size_t ws_size,
                              hipStream_t stream) {
    const float* x = (const float*)d_in[0];
    float* out = (float*)d_out;
    constexpr int total_threads = 16 * 64 * 128 * 16;   // 2,097,152
    constexpr int block = 256;
    constexpr int grid = total_threads / block;          // 8192
    iwt2d_kernel<<<grid, block, 0, stream>>>(x, out);
}

// Round 6
// 109.293 us; speedup vs baseline: 4.2340x; 1.2064x over previous
//
#include <hip/hip_runtime.h>

// Inverse 2D Haar wavelet:
//   in : (B=16, 4*CH=256, H=128, W=128) f32
//   out: (B=16, CH=64,   2H=256, 2W=256) f32
// out[b,c,2h+0,2w+0] = (LL+LH+HL+HH)*0.5
// out[b,c,2h+0,2w+1] = (LL+LH-HL-HH)*0.5
// out[b,c,2h+1,2w+0] = (LL-LH+HL-HH)*0.5
// out[b,c,2h+1,2w+1] = (LL-LH-HL+HH)*0.5
//
// R5 lesson: per-instruction lane contiguity is what matters. 8-wide/thread
// gave 32B-strided 16B accesses per instruction -> 131 us (vs R1 105).
// R6: 2 input w-positions per thread. Loads = float2 (8B/lane, fully
// contiguous 512B/wave/instr). Stores = one float4 per output row, wq spans
// 64 lanes -> each wave-instruction writes one full 1KiB output row.

__global__ __launch_bounds__(256) void iwt2d_kernel(const float* __restrict__ x,
                                                    float* __restrict__ out) {
    constexpr int B = 16, CH = 64, H = 128, W = 128;
    constexpr int WP = W / 2;                       // 64 pairs per input row
    const int t = blockIdx.x * blockDim.x + threadIdx.x;
    // total threads = B*CH*H*WP = 16*64*128*64 = 8,388,608 (grid sized exactly)
    const int wq = t & (WP - 1);                    // 0..63 — full wave in one row
    const int h  = (t >> 6) & (H - 1);
    const int c  = (t >> 13) & (CH - 1);
    const int b  = t >> 19;

    const size_t plane = (size_t)H * W;             // 16384
    const float* base = x + (size_t)b * (4 * CH) * plane + (size_t)c * plane
                          + (size_t)h * W + (size_t)wq * 2;

    const float2 ll = *(const float2*)(base);
    const float2 lh = *(const float2*)(base + (size_t)CH * plane);
    const float2 hl = *(const float2*)(base + (size_t)(2 * CH) * plane);
    const float2 hh = *(const float2*)(base + (size_t)(3 * CH) * plane);

    // j = 0 (x), j = 1 (y)
    const float s0x = ll.x + lh.x, s1x = ll.x - lh.x;
    const float s2x = hl.x + hh.x, s3x = hl.x - hh.x;
    const float s0y = ll.y + lh.y, s1y = ll.y - lh.y;
    const float s2y = hl.y + hh.y, s3y = hl.y - hh.y;

    float4 top, bot;
    top.x = (s0x + s2x) * 0.5f;   // a0
    top.y = (s0x - s2x) * 0.5f;   // b0
    top.z = (s0y + s2y) * 0.5f;   // a1
    top.w = (s0y - s2y) * 0.5f;   // b1
    bot.x = (s1x + s3x) * 0.5f;   // c0
    bot.y = (s1x - s3x) * 0.5f;   // d0
    bot.z = (s1y + s3y) * 0.5f;   // c1
    bot.w = (s1y - s3y) * 0.5f;   // d1

    const size_t oW = 2 * W;                        // 256
    const size_t oplane = (size_t)(2 * H) * oW;     // 131072
    float* orow0 = out + (size_t)b * CH * oplane + (size_t)c * oplane
                       + (size_t)(2 * h) * oW + (size_t)wq * 4;

    *(float4*)(orow0)      = top;
    *(float4*)(orow0 + oW) = bot;
}

extern "C" void kernel_launch(void* const* d_in, const int* in_sizes, int n_in,
                              void* d_out, int out_size, void* d_ws, size_t ws_size,
                              hipStream_t stream) {
    const float* x = (const float*)d_in[0];
    float* out = (float*)d_out;
    constexpr int total_threads = 16 * 64 * 128 * 64;   // 8,388,608
    constexpr int block = 256;
    constexpr int grid = total_threads / block;          // 32768
    iwt2d_kernel<<<grid, block, 0, stream>>>(x, out);
}